// Round 4
// baseline (826.753 us; speedup 1.0000x reference)
//
#include <hip/hip_runtime.h>

// Problem constants
#define Bn 131072
#define Dn 256
#define Hn 256
#define Cn 8

typedef __attribute__((ext_vector_type(4))) float f32x4;
typedef __attribute__((ext_vector_type(8))) __bf16 bf16x8;

#define LDA 40   // root LDS row stride in bf16 units (80B): <=2-way aliasing = free
#define LDH 264  // sH row stride in bf16 (264*2B=132 dwords; 132%32=4 -> <=2-way)

// ---- bf16 helpers (round-to-nearest-even) ----
__device__ inline unsigned short rtn_bf16(float v) {
    unsigned int u = __float_as_uint(v);
    unsigned int r = u + 0x7fffu + ((u >> 16) & 1u);
    return (unsigned short)(r >> 16);
}
__device__ inline float bf16_to_f(unsigned short h) {
    return __uint_as_float((unsigned int)h << 16);
}
__device__ inline void split3(float v, unsigned short& a0, unsigned short& a1,
                              unsigned short& a2) {
    a0 = rtn_bf16(v); float r = v - bf16_to_f(a0);
    a1 = rtn_bf16(r); r -= bf16_to_f(a1);
    a2 = rtn_bf16(r);
}

// ---------------------------------------------------------------------------
// Prep: W1[k][n] -> 3 bf16 splits transposed [n][k] (routing-accurate path);
//       Wc1[e][k][n] -> single bf16 transposed [e][n][k] (value-accurate path).
// ---------------------------------------------------------------------------
__global__ __launch_bounds__(256)
void prep_kernel(const float* __restrict__ W1, const float* __restrict__ Wc1,
                 unsigned short* __restrict__ W1t0, unsigned short* __restrict__ W1t1,
                 unsigned short* __restrict__ W1t2, unsigned short* __restrict__ Wc1t)
{
    const int idx = blockIdx.x * 256 + threadIdx.x;
    if (idx < 65536) {
        const int n = idx >> 8, k = idx & 255;
        unsigned short a0, a1, a2;
        split3(W1[k * 256 + n], a0, a1, a2);
        W1t0[idx] = a0; W1t1[idx] = a1; W1t2[idx] = a2;
    } else {
        const int j = idx - 65536;            // 0 .. 8*65536-1
        const int e = j >> 16, rem = j & 65535;
        const int n = rem >> 8, k = rem & 255;
        Wc1t[(e << 16) + n * 256 + k] = rtn_bf16(Wc1[(e << 16) + k * 256 + n]);
    }
}

// ---------------------------------------------------------------------------
// FUSED kernel. Root GEMM (3-split bf16 MFMA, fp32-accurate) + head + routing
// + in-block expert pass with the A-tile held in LDS:
//   k-loop -> barrier -> epilogue {h -> sH (bf16, LDS), head partials -> sP}
//   -> barrier -> routing -> barrier -> {non-routed h -> global (from acc),
//   re-zero sP, task table} -> barrier -> sOrd -> barrier -> expert tasks
//   (A: 8x ds_read_b128 from sH; B: L2-resident Wc1t) -> barrier -> logits.
// out_h is written once per row: h for non-routed rows, h_c for routed rows.
// sH is union-overlaid on the root sA buffers (dead after the k-loop).
// ---------------------------------------------------------------------------
__global__ __launch_bounds__(512, 4)
void fused_kernel(const float* __restrict__ x,
                  const unsigned short* __restrict__ Wt0,
                  const unsigned short* __restrict__ Wt1,
                  const unsigned short* __restrict__ Wt2,
                  const float* __restrict__ b1, const float* __restrict__ W2,
                  const float* __restrict__ b2, const float* __restrict__ tau,
                  const unsigned short* __restrict__ Wc1t,
                  const float* __restrict__ bc1,
                  const float* __restrict__ Wc2, const float* __restrict__ bc2,
                  float* __restrict__ out_logits, float* __restrict__ out_h,
                  float* __restrict__ out_depth)
{
    __shared__ union {
        unsigned short A[3][128 * LDA];   // 30.7 KB (root staging)
        unsigned short H[128 * LDH];      // 67.6 KB (bf16 h tile)
    } sU;                                                                     // 67.6 KB
    __shared__ float sP[128][8];                                              // 4 KB
    __shared__ int   sCnt[8], sOff[8], sBest[128], sSlot[128], sOrd[128];
    __shared__ int   sTaskE[16], sTaskM[16], sNT;

    const int t    = threadIdx.x;
    const int lane = t & 63;
    const int w    = t >> 6;
    const int tx   = lane & 15;
    const int q    = lane >> 4;
    const long r0  = (long)blockIdx.x * 128;

    if (t < 8) sCnt[t] = 0;
    ((float*)sP)[t] = 0.0f;
    ((float*)sP)[t + 512] = 0.0f;

    const int colA = w * 32 + tx;
    const int colB = colA + 16;
    const unsigned short* bp0 = Wt0 + colA * 256 + q * 8;
    const unsigned short* bp1 = Wt1 + colA * 256 + q * 8;
    const unsigned short* bp2 = Wt2 + colA * 256 + q * 8;
    const unsigned short* bp3 = Wt0 + colB * 256 + q * 8;
    const unsigned short* bp4 = Wt1 + colB * 256 + q * 8;
    const unsigned short* bp5 = Wt2 + colB * 256 + q * 8;

    f32x4 acc[8][2];
#pragma unroll
    for (int mt = 0; mt < 8; mt++)
#pragma unroll
        for (int nt = 0; nt < 2; nt++) acc[mt][nt] = (f32x4)0.0f;

    // staging map: thread t covers rows ar and ar+64 at float4-slot ak
    const int ar = t >> 3, ak = t & 7;
    const float4* xr0 = (const float4*)x + (r0 + ar) * 64 + ak;
    const float4* xr1 = (const float4*)x + (r0 + 64 + ar) * 64 + ak;
    float4 xv0 = xr0[0];
    float4 xv1 = xr1[0];

    for (int i = 0; i < 8; i++) {
        if (i) __syncthreads();             // previous iter's reads complete
        {
            unsigned short h0[4], h1[4], h2[4];
            split3(xv0.x, h0[0], h1[0], h2[0]);
            split3(xv0.y, h0[1], h1[1], h2[1]);
            split3(xv0.z, h0[2], h1[2], h2[2]);
            split3(xv0.w, h0[3], h1[3], h2[3]);
            *(ushort4*)&sU.A[0][ar * LDA + ak * 4] = make_ushort4(h0[0], h0[1], h0[2], h0[3]);
            *(ushort4*)&sU.A[1][ar * LDA + ak * 4] = make_ushort4(h1[0], h1[1], h1[2], h1[3]);
            *(ushort4*)&sU.A[2][ar * LDA + ak * 4] = make_ushort4(h2[0], h2[1], h2[2], h2[3]);
            split3(xv1.x, h0[0], h1[0], h2[0]);
            split3(xv1.y, h0[1], h1[1], h2[1]);
            split3(xv1.z, h0[2], h1[2], h2[2]);
            split3(xv1.w, h0[3], h1[3], h2[3]);
            *(ushort4*)&sU.A[0][(64 + ar) * LDA + ak * 4] = make_ushort4(h0[0], h0[1], h0[2], h0[3]);
            *(ushort4*)&sU.A[1][(64 + ar) * LDA + ak * 4] = make_ushort4(h1[0], h1[1], h1[2], h1[3]);
            *(ushort4*)&sU.A[2][(64 + ar) * LDA + ak * 4] = make_ushort4(h2[0], h2[1], h2[2], h2[3]);
        }
        if (i < 7) { xv0 = xr0[(i + 1) * 8]; xv1 = xr1[(i + 1) * 8]; }
        __syncthreads();

        const int ko = i * 32;
        const bf16x8 B0 = *(const bf16x8*)(bp0 + ko);
        const bf16x8 B1 = *(const bf16x8*)(bp1 + ko);
        const bf16x8 B2 = *(const bf16x8*)(bp2 + ko);
        const bf16x8 B3 = *(const bf16x8*)(bp3 + ko);
        const bf16x8 B4 = *(const bf16x8*)(bp4 + ko);
        const bf16x8 B5 = *(const bf16x8*)(bp5 + ko);

#pragma unroll
        for (int mt = 0; mt < 8; mt++) {
            const bf16x8 A0 = *(const bf16x8*)&sU.A[0][(mt * 16 + tx) * LDA + q * 8];
            const bf16x8 A1 = *(const bf16x8*)&sU.A[1][(mt * 16 + tx) * LDA + q * 8];
            const bf16x8 A2 = *(const bf16x8*)&sU.A[2][(mt * 16 + tx) * LDA + q * 8];
            acc[mt][0] = __builtin_amdgcn_mfma_f32_16x16x32_bf16(A0, B0, acc[mt][0], 0, 0, 0);
            acc[mt][0] = __builtin_amdgcn_mfma_f32_16x16x32_bf16(A0, B1, acc[mt][0], 0, 0, 0);
            acc[mt][0] = __builtin_amdgcn_mfma_f32_16x16x32_bf16(A1, B0, acc[mt][0], 0, 0, 0);
            acc[mt][0] = __builtin_amdgcn_mfma_f32_16x16x32_bf16(A1, B1, acc[mt][0], 0, 0, 0);
            acc[mt][0] = __builtin_amdgcn_mfma_f32_16x16x32_bf16(A0, B2, acc[mt][0], 0, 0, 0);
            acc[mt][0] = __builtin_amdgcn_mfma_f32_16x16x32_bf16(A2, B0, acc[mt][0], 0, 0, 0);
            acc[mt][1] = __builtin_amdgcn_mfma_f32_16x16x32_bf16(A0, B3, acc[mt][1], 0, 0, 0);
            acc[mt][1] = __builtin_amdgcn_mfma_f32_16x16x32_bf16(A0, B4, acc[mt][1], 0, 0, 0);
            acc[mt][1] = __builtin_amdgcn_mfma_f32_16x16x32_bf16(A1, B3, acc[mt][1], 0, 0, 0);
            acc[mt][1] = __builtin_amdgcn_mfma_f32_16x16x32_bf16(A1, B4, acc[mt][1], 0, 0, 0);
            acc[mt][1] = __builtin_amdgcn_mfma_f32_16x16x32_bf16(A0, B5, acc[mt][1], 0, 0, 0);
            acc[mt][1] = __builtin_amdgcn_mfma_f32_16x16x32_bf16(A2, B3, acc[mt][1], 0, 0, 0);
        }
    }
    __syncthreads();   // ALL waves done reading sU.A -> safe to overwrite as sU.H

    // ---- epilogue: bias+relu, h -> sH (bf16), fp32 head partials ----
    const float b1c0 = b1[colA], b1c1 = b1[colB];
    float w20[8], w21[8];
    {
        const float4 a0 = ((const float4*)W2)[colA * 2];
        const float4 a1 = ((const float4*)W2)[colA * 2 + 1];
        const float4 c0 = ((const float4*)W2)[colB * 2];
        const float4 c1 = ((const float4*)W2)[colB * 2 + 1];
        w20[0]=a0.x; w20[1]=a0.y; w20[2]=a0.z; w20[3]=a0.w;
        w20[4]=a1.x; w20[5]=a1.y; w20[6]=a1.z; w20[7]=a1.w;
        w21[0]=c0.x; w21[1]=c0.y; w21[2]=c0.z; w21[3]=c0.w;
        w21[4]=c1.x; w21[5]=c1.y; w21[6]=c1.z; w21[7]=c1.w;
    }

#pragma unroll
    for (int mt = 0; mt < 8; mt++) {
        float pm[4][8];
#pragma unroll
        for (int reg = 0; reg < 4; reg++) {
            const float h0 = fmaxf(acc[mt][0][reg] + b1c0, 0.0f);
            const float h1 = fmaxf(acc[mt][1][reg] + b1c1, 0.0f);
            const int row = mt * 16 + q * 4 + reg;
            sU.H[row * LDH + colA] = rtn_bf16(h0);
            sU.H[row * LDH + colB] = rtn_bf16(h1);
#pragma unroll
            for (int c = 0; c < 8; c++)
                pm[reg][c] = h0 * w20[c] + h1 * w21[c];
        }
#pragma unroll
        for (int reg = 0; reg < 4; reg++)
#pragma unroll
            for (int c = 0; c < 8; c++) {
                float v = pm[reg][c];
                v += __shfl_xor(v, 1, 16);
                v += __shfl_xor(v, 2, 16);
                v += __shfl_xor(v, 4, 16);
                v += __shfl_xor(v, 8, 16);
                if (tx == 0) atomicAdd(&sP[mt * 16 + q * 4 + reg][c], v);
            }
    }
    __syncthreads();

    // ---- routing: one thread per row ----
    if (t < 128) {
        const long row = r0 + t;
        float l[8];
        float mx = -1e30f;
#pragma unroll
        for (int c = 0; c < 8; c++) {
            l[c] = sP[t][c] + b2[c];
            mx = fmaxf(mx, l[c]);
        }
        float e[8], s = 0.0f;
#pragma unroll
        for (int c = 0; c < 8; c++) { e[c] = expf(l[c] - mx); s += e[c]; }
        const float inv = 1.0f / s;
        int best = 0; float bp = -1.0f;
#pragma unroll
        for (int c = 0; c < 8; c++) {
            const float pr = e[c] * inv;
            const float m  = (pr >= tau[c]) ? pr : -1.0f;
            if (m > bp) { bp = m; best = c; }   // strict > == first max (jnp.argmax)
        }
        const bool routed = (bp >= 0.0f);
        out_depth[row] = routed ? 1.0f : 0.0f;
        if (routed) {
            sSlot[t] = atomicAdd(&sCnt[best], 1);
            sBest[t] = best;
        } else {
            sBest[t] = -1;
            // root logits are final only for non-routed rows
            float4* lo4 = (float4*)&out_logits[row * 8];
            lo4[0] = make_float4(l[0], l[1], l[2], l[3]);
            lo4[1] = make_float4(l[4], l[5], l[6], l[7]);
        }
    }
    __syncthreads();

    // ---- non-routed rows: out_h = h (from live acc); re-zero sP; tasks ----
#pragma unroll
    for (int mt = 0; mt < 8; mt++)
#pragma unroll
        for (int reg = 0; reg < 4; reg++) {
            const int row = mt * 16 + q * 4 + reg;
            if (sBest[row] < 0) {
                out_h[(r0 + row) * 256 + colA] = fmaxf(acc[mt][0][reg] + b1c0, 0.0f);
                out_h[(r0 + row) * 256 + colB] = fmaxf(acc[mt][1][reg] + b1c1, 0.0f);
            }
        }
    ((float*)sP)[t] = 0.0f;
    ((float*)sP)[t + 512] = 0.0f;
    if (t == 0) {
        int off = 0, T = 0;
        for (int e = 0; e < 8; e++) {
            sOff[e] = off;
            const int n = sCnt[e];
            for (int m = 0; m * 16 < n; m++) { sTaskE[T] = e; sTaskM[T] = m; T++; }
            off += n;
        }
        sNT = T;
    }
    __syncthreads();
    if (t < 128 && sBest[t] >= 0)
        sOrd[sOff[sBest[t]] + sSlot[t]] = t;
    __syncthreads();

    // ---- expert phase: waves grab (expert, 16-row tile) tasks; no barriers.
    //      A from sH (LDS), B from L2-resident Wc1t. Rows disjoint.        ----
    for (int task = w; task < sNT; task += 8) {
        const int e   = sTaskE[task];
        const int m0  = sTaskM[task] << 4;
        const int ce  = sCnt[e];
        const int be  = sOff[e];
        const int my  = m0 + tx;
        const int lr  = sOrd[be + (my < ce ? my : 0)];   // A-row (dup row0 if pad)

        int  orow[4]; bool oval[4];
#pragma unroll
        for (int reg = 0; reg < 4; reg++) {
            const int rr = m0 + q * 4 + reg;
            oval[reg] = rr < ce;
            orow[reg] = oval[reg] ? sOrd[be + rr] : 0;
        }

        // A-fragments for the full k=0..255 row, straight from LDS.
        const unsigned short* hlds = &sU.H[lr * LDH + q * 8];
        bf16x8 Af[8];
#pragma unroll
        for (int j = 0; j < 8; j++)
            Af[j] = *(const bf16x8*)&hlds[j * 32];

        const unsigned short* We = Wc1t + (e << 16);
        const float* bc1e = bc1 + (e << 8);
        const float* w2e  = Wc2 + e * (Hn * Cn);

#pragma unroll
        for (int half = 0; half < 2; half++) {
            const int cb = half << 7;
            f32x4 ac[8];
#pragma unroll
            for (int nt = 0; nt < 8; nt++) ac[nt] = (f32x4)0.0f;

#pragma unroll
            for (int kh = 0; kh < 2; kh++) {
#pragma unroll
                for (int nt = 0; nt < 8; nt++) {
                    const unsigned short* bp = We + (cb + nt * 16 + tx) * 256 + kh * 128 + q * 8;
#pragma unroll
                    for (int j = 0; j < 4; j++) {
                        const bf16x8 Bf = *(const bf16x8*)(bp + j * 32);
                        ac[nt] = __builtin_amdgcn_mfma_f32_16x16x32_bf16(Af[kh * 4 + j], Bf, ac[nt], 0, 0, 0);
                    }
                }
            }

            // per-half epilogue: relu + store h_c (routed rows), head partials
            float pm[4][8];
#pragma unroll
            for (int reg = 0; reg < 4; reg++)
#pragma unroll
                for (int c = 0; c < 8; c++) pm[reg][c] = 0.0f;

#pragma unroll
            for (int nt = 0; nt < 8; nt++) {
                const int col = cb + nt * 16 + tx;
                const float bb = bc1e[col];
                const float4 wa = ((const float4*)w2e)[col * 2];
                const float4 wb = ((const float4*)w2e)[col * 2 + 1];
#pragma unroll
                for (int reg = 0; reg < 4; reg++) {
                    const float hc = fmaxf(ac[nt][reg] + bb, 0.0f);
                    if (oval[reg])
                        out_h[(r0 + orow[reg]) * 256 + col] = hc;
                    pm[reg][0] += hc * wa.x; pm[reg][1] += hc * wa.y;
                    pm[reg][2] += hc * wa.z; pm[reg][3] += hc * wa.w;
                    pm[reg][4] += hc * wb.x; pm[reg][5] += hc * wb.y;
                    pm[reg][6] += hc * wb.z; pm[reg][7] += hc * wb.w;
                }
            }
#pragma unroll
            for (int reg = 0; reg < 4; reg++)
#pragma unroll
                for (int c = 0; c < 8; c++) {
                    float v = pm[reg][c];
                    v += __shfl_xor(v, 1, 16);
                    v += __shfl_xor(v, 2, 16);
                    v += __shfl_xor(v, 4, 16);
                    v += __shfl_xor(v, 8, 16);
                    if (tx == 0 && oval[reg]) atomicAdd(&sP[orow[reg]][c], v);
                }
        }
    }
    __syncthreads();

    // ---- final logits for routed rows ----
    if (t < 128 && sBest[t] >= 0) {
        const float* b2e = bc2 + sBest[t] * Cn;
        float4* lo4 = (float4*)&out_logits[(r0 + t) * 8];
        lo4[0] = make_float4(sP[t][0] + b2e[0], sP[t][1] + b2e[1],
                             sP[t][2] + b2e[2], sP[t][3] + b2e[3]);
        lo4[1] = make_float4(sP[t][4] + b2e[4], sP[t][5] + b2e[5],
                             sP[t][6] + b2e[6], sP[t][7] + b2e[7]);
    }
}

extern "C" void kernel_launch(void* const* d_in, const int* in_sizes, int n_in,
                              void* d_out, int out_size, void* d_ws, size_t ws_size,
                              hipStream_t stream)
{
    const float* x   = (const float*)d_in[0];
    const float* W1  = (const float*)d_in[1];
    const float* b1  = (const float*)d_in[2];
    const float* W2  = (const float*)d_in[3];
    const float* b2  = (const float*)d_in[4];
    const float* Wc1 = (const float*)d_in[5];
    const float* bc1 = (const float*)d_in[6];
    const float* Wc2 = (const float*)d_in[7];
    const float* bc2 = (const float*)d_in[8];
    const float* tau = (const float*)d_in[9];

    float* out_logits = (float*)d_out;                       // [B, 8]
    float* out_h      = out_logits + (long)Bn * Cn;          // [B, 256]
    float* out_depth  = out_h + (long)Bn * Hn;               // [B]

    char* wsb = (char*)d_ws;
    unsigned short* W1t0 = (unsigned short*)wsb;
    unsigned short* W1t1 = W1t0 + 65536;
    unsigned short* W1t2 = W1t1 + 65536;
    unsigned short* Wc1t = W1t2 + 65536;                     // 8 x 65536 bf16

    prep_kernel<<<dim3((65536 + 8 * 65536) / 256), 256, 0, stream>>>(
        W1, Wc1, W1t0, W1t1, W1t2, Wc1t);

    fused_kernel<<<dim3(Bn / 128), 512, 0, stream>>>(
        x, W1t0, W1t1, W1t2, b1, W2, b2, tau, Wc1t, bc1, Wc2, bc2,
        out_logits, out_h, out_depth);
}

// Round 5
// 599.881 us; speedup vs baseline: 1.3782x; 1.3782x over previous
//
#include <hip/hip_runtime.h>

// Problem constants
#define Bn 131072
#define Dn 256
#define Hn 256
#define Cn 8

typedef __attribute__((ext_vector_type(4))) float f32x4;
typedef __attribute__((ext_vector_type(8))) __bf16 bf16x8;
typedef _Float16 f16;
typedef __attribute__((ext_vector_type(8))) _Float16 f16x8;

#define LDA 40   // LDS row stride in bf16/f16 units (80B): <=2-way bank aliasing = free

// ---- bf16 helpers (round-to-nearest-even) ----
__device__ inline unsigned short rtn_bf16(float v) {
    unsigned int u = __float_as_uint(v);
    unsigned int r = u + 0x7fffu + ((u >> 16) & 1u);
    return (unsigned short)(r >> 16);
}
__device__ inline float bf16_to_f(unsigned short h) {
    return __uint_as_float((unsigned int)h << 16);
}
__device__ inline ushort4 cvt4(float4 v) {
    return make_ushort4(rtn_bf16(v.x), rtn_bf16(v.y), rtn_bf16(v.z), rtn_bf16(v.w));
}
// ---- f16 2-split: v = h0 + h1 + O(2^-24 v).  (f32->f16 cast is RTN.) ----
__device__ inline void split2h(float v, unsigned short& a0, unsigned short& a1) {
    const f16 h0 = (f16)v;
    const f16 h1 = (f16)(v - (float)h0);
    a0 = __builtin_bit_cast(unsigned short, h0);
    a1 = __builtin_bit_cast(unsigned short, h1);
}

// ---------------------------------------------------------------------------
// Prep: W1[k][n] -> 2 f16 splits transposed [n][k] (routing-accurate path);
//       Wc1[e][k][n] -> single bf16 transposed [e][n][k] (value-accurate path).
// ---------------------------------------------------------------------------
__global__ __launch_bounds__(256)
void prep_kernel(const float* __restrict__ W1, const float* __restrict__ Wc1,
                 unsigned short* __restrict__ W1t0, unsigned short* __restrict__ W1t1,
                 unsigned short* __restrict__ Wc1t)
{
    const int idx = blockIdx.x * 256 + threadIdx.x;
    if (idx < 65536) {
        const int n = idx >> 8, k = idx & 255;
        unsigned short a0, a1;
        split2h(W1[k * 256 + n], a0, a1);
        W1t0[idx] = a0; W1t1[idx] = a1;
    } else {
        const int j = idx - 65536;            // 0 .. 8*65536-1
        const int e = j >> 16, rem = j & 65535;
        const int n = rem >> 8, k = rem & 255;
        Wc1t[(e << 16) + n * 256 + k] = rtn_bf16(Wc1[(e << 16) + k * 256 + n]);
    }
}

// ---------------------------------------------------------------------------
// Phase A: h = relu(x@W1+b1) via f16 2-split / 3-product MFMA (error ~2^-22
// relative, fp32-class — needed for the tau-threshold routing);
// logits = h@W2+b2 fp32; routing. Block: 512 threads (8 waves), tile =
// 128 rows x 256 cols; wave w owns cols [w*32,w*32+32) as 2 n-tiles;
// 8 m-tiles of 16. Single-buffer LDS A (proven round-0 structure).
// ---------------------------------------------------------------------------
__global__ __launch_bounds__(512, 4)
void root_kernel(const float* __restrict__ x,
                 const unsigned short* __restrict__ Wt0,
                 const unsigned short* __restrict__ Wt1,
                 const float* __restrict__ b1, const float* __restrict__ W2,
                 const float* __restrict__ b2, const float* __restrict__ tau,
                 float* __restrict__ out_logits, float* __restrict__ out_h,
                 float* __restrict__ out_depth, int* __restrict__ cnt,
                 int* __restrict__ lists)
{
    __shared__ unsigned short sA0[128 * LDA], sA1[128 * LDA];   // 20.5 KB
    __shared__ float sP[128][8];                                // 4 KB
    __shared__ int   sCnt[8], sBase[8], sBest[128], sSlot[128];

    const int t    = threadIdx.x;
    const int lane = t & 63;
    const int w    = t >> 6;
    const int tx   = lane & 15;
    const int q    = lane >> 4;
    const long r0  = (long)blockIdx.x * 128;

    if (t < 8) sCnt[t] = 0;
    ((float*)sP)[t] = 0.0f;
    ((float*)sP)[t + 512] = 0.0f;

    const int colA = w * 32 + tx;
    const int colB = colA + 16;
    const unsigned short* bp0 = Wt0 + colA * 256 + q * 8;  // G0 colA
    const unsigned short* bp1 = Wt1 + colA * 256 + q * 8;  // G1 colA
    const unsigned short* bp2 = Wt0 + colB * 256 + q * 8;  // G0 colB
    const unsigned short* bp3 = Wt1 + colB * 256 + q * 8;  // G1 colB

    f32x4 acc[8][2];
#pragma unroll
    for (int mt = 0; mt < 8; mt++)
#pragma unroll
        for (int nt = 0; nt < 2; nt++) acc[mt][nt] = (f32x4)0.0f;

    // staging map: thread t covers rows ar and ar+64 at float4-slot ak
    const int ar = t >> 3, ak = t & 7;
    const float4* xr0 = (const float4*)x + (r0 + ar) * 64 + ak;
    const float4* xr1 = (const float4*)x + (r0 + 64 + ar) * 64 + ak;
    float4 xv0 = xr0[0];
    float4 xv1 = xr1[0];

    for (int i = 0; i < 8; i++) {
        if (i) __syncthreads();             // previous iter's reads complete
        {
            unsigned short h0[4], h1[4];
            split2h(xv0.x, h0[0], h1[0]);
            split2h(xv0.y, h0[1], h1[1]);
            split2h(xv0.z, h0[2], h1[2]);
            split2h(xv0.w, h0[3], h1[3]);
            *(ushort4*)&sA0[ar * LDA + ak * 4] = make_ushort4(h0[0], h0[1], h0[2], h0[3]);
            *(ushort4*)&sA1[ar * LDA + ak * 4] = make_ushort4(h1[0], h1[1], h1[2], h1[3]);
            split2h(xv1.x, h0[0], h1[0]);
            split2h(xv1.y, h0[1], h1[1]);
            split2h(xv1.z, h0[2], h1[2]);
            split2h(xv1.w, h0[3], h1[3]);
            *(ushort4*)&sA0[(64 + ar) * LDA + ak * 4] = make_ushort4(h0[0], h0[1], h0[2], h0[3]);
            *(ushort4*)&sA1[(64 + ar) * LDA + ak * 4] = make_ushort4(h1[0], h1[1], h1[2], h1[3]);
        }
        if (i < 7) { xv0 = xr0[(i + 1) * 8]; xv1 = xr1[(i + 1) * 8]; }
        __syncthreads();

        const int ko = i * 32;
        const f16x8 B0 = *(const f16x8*)(bp0 + ko);
        const f16x8 B1 = *(const f16x8*)(bp1 + ko);
        const f16x8 B2 = *(const f16x8*)(bp2 + ko);
        const f16x8 B3 = *(const f16x8*)(bp3 + ko);

#pragma unroll
        for (int mt = 0; mt < 8; mt++) {
            const f16x8 A0 = *(const f16x8*)&sA0[(mt * 16 + tx) * LDA + q * 8];
            const f16x8 A1 = *(const f16x8*)&sA1[(mt * 16 + tx) * LDA + q * 8];
            // (A0+A1)(G0+G1) ~= A0G0 + A0G1 + A1G0   (drop A1G1 ~ 2^-22)
            acc[mt][0] = __builtin_amdgcn_mfma_f32_16x16x32_f16(A0, B0, acc[mt][0], 0, 0, 0);
            acc[mt][0] = __builtin_amdgcn_mfma_f32_16x16x32_f16(A0, B1, acc[mt][0], 0, 0, 0);
            acc[mt][0] = __builtin_amdgcn_mfma_f32_16x16x32_f16(A1, B0, acc[mt][0], 0, 0, 0);
            acc[mt][1] = __builtin_amdgcn_mfma_f32_16x16x32_f16(A0, B2, acc[mt][1], 0, 0, 0);
            acc[mt][1] = __builtin_amdgcn_mfma_f32_16x16x32_f16(A0, B3, acc[mt][1], 0, 0, 0);
            acc[mt][1] = __builtin_amdgcn_mfma_f32_16x16x32_f16(A1, B2, acc[mt][1], 0, 0, 0);
        }
    }

    // ---- epilogue: bias+relu, store h, fp32 head partials ----
    const float b1c0 = b1[colA], b1c1 = b1[colB];
    float w20[8], w21[8];
    {
        const float4 a0 = ((const float4*)W2)[colA * 2];
        const float4 a1 = ((const float4*)W2)[colA * 2 + 1];
        const float4 c0 = ((const float4*)W2)[colB * 2];
        const float4 c1 = ((const float4*)W2)[colB * 2 + 1];
        w20[0]=a0.x; w20[1]=a0.y; w20[2]=a0.z; w20[3]=a0.w;
        w20[4]=a1.x; w20[5]=a1.y; w20[6]=a1.z; w20[7]=a1.w;
        w21[0]=c0.x; w21[1]=c0.y; w21[2]=c0.z; w21[3]=c0.w;
        w21[4]=c1.x; w21[5]=c1.y; w21[6]=c1.z; w21[7]=c1.w;
    }

#pragma unroll
    for (int mt = 0; mt < 8; mt++) {
        float pm[4][8];
#pragma unroll
        for (int reg = 0; reg < 4; reg++) {
            const float h0 = fmaxf(acc[mt][0][reg] + b1c0, 0.0f);
            const float h1 = fmaxf(acc[mt][1][reg] + b1c1, 0.0f);
            const int row = mt * 16 + q * 4 + reg;
            out_h[(r0 + row) * 256 + colA] = h0;
            out_h[(r0 + row) * 256 + colB] = h1;
#pragma unroll
            for (int c = 0; c < 8; c++)
                pm[reg][c] = h0 * w20[c] + h1 * w21[c];
        }
#pragma unroll
        for (int reg = 0; reg < 4; reg++)
#pragma unroll
            for (int c = 0; c < 8; c++) {
                float v = pm[reg][c];
                v += __shfl_xor(v, 1, 16);
                v += __shfl_xor(v, 2, 16);
                v += __shfl_xor(v, 4, 16);
                v += __shfl_xor(v, 8, 16);
                if (tx == 0) atomicAdd(&sP[mt * 16 + q * 4 + reg][c], v);
            }
    }
    __syncthreads();

    // ---- routing: one thread per row ----
    if (t < 128) {
        const long row = r0 + t;
        float l[8];
        float mx = -1e30f;
#pragma unroll
        for (int c = 0; c < 8; c++) {
            l[c] = sP[t][c] + b2[c];
            mx = fmaxf(mx, l[c]);
        }
        float e[8], s = 0.0f;
#pragma unroll
        for (int c = 0; c < 8; c++) { e[c] = expf(l[c] - mx); s += e[c]; }
        const float inv = 1.0f / s;
        int best = 0; float bp = -1.0f;
#pragma unroll
        for (int c = 0; c < 8; c++) {
            const float pr = e[c] * inv;
            const float m  = (pr >= tau[c]) ? pr : -1.0f;
            if (m > bp) { bp = m; best = c; }   // strict > == first max (jnp.argmax)
        }
        const bool routed = (bp >= 0.0f);
        float4* lo4 = (float4*)&out_logits[row * 8];
        lo4[0] = make_float4(l[0], l[1], l[2], l[3]);
        lo4[1] = make_float4(l[4], l[5], l[6], l[7]);
        out_depth[row] = routed ? 1.0f : 0.0f;
        if (routed) {
            sSlot[t] = atomicAdd(&sCnt[best], 1);
            sBest[t] = best;
        } else {
            sBest[t] = -1;
        }
    }
    __syncthreads();
    if (t < 8) sBase[t] = sCnt[t] ? atomicAdd(&cnt[t], sCnt[t]) : 0;
    __syncthreads();
    if (t < 128 && sBest[t] >= 0) {
        const int e = sBest[t];
        lists[(long)e * Bn + sBase[e] + sSlot[t]] = (int)(r0 + t);
    }
}

// ---------------------------------------------------------------------------
// Phase B: routed rows of expert e: h_c = relu(h@Wc1[e]+bc1[e]) in PLAIN bf16
// (error ~4e-3 << 8.4e-2 threshold; routing already fixed by root);
// l_c = h_c@Wc2[e]+bc2[e] fp32. Tile = 128 rows, double-buffered LDS A.
// ---------------------------------------------------------------------------
__global__ __launch_bounds__(512, 4)
void expert_kernel(const unsigned short* __restrict__ Wc1t,
                   const float* __restrict__ bc1,
                   const float* __restrict__ Wc2, const float* __restrict__ bc2,
                   float* __restrict__ out_logits, float* __restrict__ out_h,
                   const int* __restrict__ cnt, const int* __restrict__ lists)
{
    const int e = blockIdx.y;
    const int n = cnt[e];
    const int tile0 = blockIdx.x * 128;
    if (tile0 >= n) return;
    const int nrows = min(128, n - tile0);

    __shared__ unsigned short sA[2][128 * LDA];   // 20.5 KB
    __shared__ float sP[128][8];                  // 4 KB
    __shared__ int   sRidx[128];

    const int t    = threadIdx.x;
    const int lane = t & 63;
    const int w    = t >> 6;
    const int tx   = lane & 15;
    const int q    = lane >> 4;

    if (t < 128) sRidx[t] = lists[(long)e * Bn + tile0 + min(t, nrows - 1)];
    ((float*)sP)[t] = 0.0f;
    ((float*)sP)[t + 512] = 0.0f;

    const unsigned short* W = Wc1t + (long)e * 65536;
    const int colA = w * 32 + tx;
    const int colB = colA + 16;
    const unsigned short* bpA = W + colA * 256 + q * 8;
    const unsigned short* bpB = W + colB * 256 + q * 8;

    f32x4 acc[8][2];
#pragma unroll
    for (int mt = 0; mt < 8; mt++)
#pragma unroll
        for (int nt = 0; nt < 2; nt++) acc[mt][nt] = (f32x4)0.0f;

    const int ar = t >> 3, ak = t & 7;
    __syncthreads();   // sRidx visible
    const float4* hr0 = (const float4*)out_h + (long)sRidx[ar] * 64 + ak;
    const float4* hr1 = (const float4*)out_h + (long)sRidx[64 + ar] * 64 + ak;

    float4 xv0 = hr0[0], xv1 = hr1[0];
    *(ushort4*)&sA[0][ar * LDA + ak * 4]        = cvt4(xv0);
    *(ushort4*)&sA[0][(64 + ar) * LDA + ak * 4] = cvt4(xv1);
    xv0 = hr0[8]; xv1 = hr1[8];
    bf16x8 BcA = *(const bf16x8*)(bpA);
    bf16x8 BcB = *(const bf16x8*)(bpB);
    __syncthreads();

#pragma unroll 2
    for (int i = 0; i < 8; i++) {
        const int cur = i & 1;
        if (i < 7) {
            *(ushort4*)&sA[cur ^ 1][ar * LDA + ak * 4]        = cvt4(xv0);
            *(ushort4*)&sA[cur ^ 1][(64 + ar) * LDA + ak * 4] = cvt4(xv1);
            if (i < 6) { xv0 = hr0[(i + 2) * 8]; xv1 = hr1[(i + 2) * 8]; }
        }
        bf16x8 BnA, BnB;
        if (i < 7) {
            BnA = *(const bf16x8*)(bpA + (i + 1) * 32);
            BnB = *(const bf16x8*)(bpB + (i + 1) * 32);
        }
#pragma unroll
        for (int mt = 0; mt < 8; mt++) {
            const bf16x8 A = *(const bf16x8*)&sA[cur][(mt * 16 + tx) * LDA + q * 8];
            acc[mt][0] = __builtin_amdgcn_mfma_f32_16x16x32_bf16(A, BcA, acc[mt][0], 0, 0, 0);
            acc[mt][1] = __builtin_amdgcn_mfma_f32_16x16x32_bf16(A, BcB, acc[mt][1], 0, 0, 0);
        }
        if (i < 7) { BcA = BnA; BcB = BnB; }
        __syncthreads();
    }

    // ---- epilogue ----
    const float* bc1e = bc1 + (long)e * Hn;
    const float b1c0 = bc1e[colA], b1c1 = bc1e[colB];
    const float* W2c = Wc2 + (long)e * Hn * Cn;
    float w20[8], w21[8];
    {
        const float4 a0 = ((const float4*)W2c)[colA * 2];
        const float4 a1 = ((const float4*)W2c)[colA * 2 + 1];
        const float4 c0 = ((const float4*)W2c)[colB * 2];
        const float4 c1 = ((const float4*)W2c)[colB * 2 + 1];
        w20[0]=a0.x; w20[1]=a0.y; w20[2]=a0.z; w20[3]=a0.w;
        w20[4]=a1.x; w20[5]=a1.y; w20[6]=a1.z; w20[7]=a1.w;
        w21[0]=c0.x; w21[1]=c0.y; w21[2]=c0.z; w21[3]=c0.w;
        w21[4]=c1.x; w21[5]=c1.y; w21[6]=c1.z; w21[7]=c1.w;
    }

#pragma unroll
    for (int mt = 0; mt < 8; mt++) {
        float pm[4][8];
#pragma unroll
        for (int reg = 0; reg < 4; reg++) {
            const float h0 = fmaxf(acc[mt][0][reg] + b1c0, 0.0f);
            const float h1 = fmaxf(acc[mt][1][reg] + b1c1, 0.0f);
            const int row = mt * 16 + q * 4 + reg;
            if (row < nrows) {
                out_h[(long)sRidx[row] * 256 + colA] = h0;
                out_h[(long)sRidx[row] * 256 + colB] = h1;
            }
#pragma unroll
            for (int c = 0; c < 8; c++)
                pm[reg][c] = h0 * w20[c] + h1 * w21[c];
        }
#pragma unroll
        for (int reg = 0; reg < 4; reg++)
#pragma unroll
            for (int c = 0; c < 8; c++) {
                float v = pm[reg][c];
                v += __shfl_xor(v, 1, 16);
                v += __shfl_xor(v, 2, 16);
                v += __shfl_xor(v, 4, 16);
                v += __shfl_xor(v, 8, 16);
                if (tx == 0) atomicAdd(&sP[mt * 16 + q * 4 + reg][c], v);
            }
    }
    __syncthreads();

    if (t < nrows) {
        const long row = sRidx[t];
        const float* bc2e = bc2 + (long)e * Cn;
        float4* lo4 = (float4*)&out_logits[row * 8];
        lo4[0] = make_float4(sP[t][0] + bc2e[0], sP[t][1] + bc2e[1],
                             sP[t][2] + bc2e[2], sP[t][3] + bc2e[3]);
        lo4[1] = make_float4(sP[t][4] + bc2e[4], sP[t][5] + bc2e[5],
                             sP[t][6] + bc2e[6], sP[t][7] + bc2e[7]);
    }
}

extern "C" void kernel_launch(void* const* d_in, const int* in_sizes, int n_in,
                              void* d_out, int out_size, void* d_ws, size_t ws_size,
                              hipStream_t stream)
{
    const float* x   = (const float*)d_in[0];
    const float* W1  = (const float*)d_in[1];
    const float* b1  = (const float*)d_in[2];
    const float* W2  = (const float*)d_in[3];
    const float* b2  = (const float*)d_in[4];
    const float* Wc1 = (const float*)d_in[5];
    const float* bc1 = (const float*)d_in[6];
    const float* Wc2 = (const float*)d_in[7];
    const float* bc2 = (const float*)d_in[8];
    const float* tau = (const float*)d_in[9];

    float* out_logits = (float*)d_out;                       // [B, 8]
    float* out_h      = out_logits + (long)Bn * Cn;          // [B, 256]
    float* out_depth  = out_h + (long)Bn * Hn;               // [B]

    char* wsb = (char*)d_ws;
    int* cnt   = (int*)wsb;                                  // 8 counters
    int* lists = (int*)(wsb + 128);                          // 8 x B ints (4MB)
    unsigned short* W1t0 = (unsigned short*)(wsb + 128 + (size_t)8 * Bn * 4);
    unsigned short* W1t1 = W1t0 + 65536;
    unsigned short* Wc1t = W1t1 + 65536;                     // 8 x 65536 bf16

    hipMemsetAsync(d_ws, 0, 128, stream);

    prep_kernel<<<dim3((65536 + 8 * 65536) / 256), 256, 0, stream>>>(
        W1, Wc1, W1t0, W1t1, Wc1t);

    root_kernel<<<dim3(Bn / 128), 512, 0, stream>>>(
        x, W1t0, W1t1, b1, W2, b2, tau, out_logits, out_h, out_depth,
        cnt, lists);

    expert_kernel<<<dim3(Bn / 128, 8), 512, 0, stream>>>(
        Wc1t, bc1, Wc2, bc2, out_logits, out_h, cnt, lists);
}

// Round 6
// 564.153 us; speedup vs baseline: 1.4655x; 1.0633x over previous
//
#include <hip/hip_runtime.h>

// Problem constants
#define Bn 131072
#define Dn 256
#define Hn 256
#define Cn 8

typedef __attribute__((ext_vector_type(4))) float f32x4;
typedef __attribute__((ext_vector_type(8))) __bf16 bf16x8;
typedef _Float16 f16;
typedef __attribute__((ext_vector_type(8))) _Float16 f16x8;

#define LDA 40   // LDS row stride in bf16/f16 units (80B): <=2-way bank aliasing = free

// ---- bf16 helpers (round-to-nearest-even) ----
__device__ inline unsigned short rtn_bf16(float v) {
    unsigned int u = __float_as_uint(v);
    unsigned int r = u + 0x7fffu + ((u >> 16) & 1u);
    return (unsigned short)(r >> 16);
}
__device__ inline float bf16_to_f(unsigned short h) {
    return __uint_as_float((unsigned int)h << 16);
}
__device__ inline ushort4 cvt4(float4 v) {
    return make_ushort4(rtn_bf16(v.x), rtn_bf16(v.y), rtn_bf16(v.z), rtn_bf16(v.w));
}
// ---- f16 2-split: v = h0 + h1 + O(2^-24 v).  (f32->f16 cast is RTN.) ----
__device__ inline void split2h(float v, unsigned short& a0, unsigned short& a1) {
    const f16 h0 = (f16)v;
    const f16 h1 = (f16)(v - (float)h0);
    a0 = __builtin_bit_cast(unsigned short, h0);
    a1 = __builtin_bit_cast(unsigned short, h1);
}

// ---------------------------------------------------------------------------
// Prep: W1[k][n] -> 2 f16 splits transposed [n][k] (routing-accurate path);
//       Wc1[e][k][n] -> single bf16 transposed [e][n][k] (value-accurate path).
// ---------------------------------------------------------------------------
__global__ __launch_bounds__(256)
void prep_kernel(const float* __restrict__ W1, const float* __restrict__ Wc1,
                 unsigned short* __restrict__ W1t0, unsigned short* __restrict__ W1t1,
                 unsigned short* __restrict__ Wc1t)
{
    const int idx = blockIdx.x * 256 + threadIdx.x;
    if (idx < 65536) {
        const int n = idx >> 8, k = idx & 255;
        unsigned short a0, a1;
        split2h(W1[k * 256 + n], a0, a1);
        W1t0[idx] = a0; W1t1[idx] = a1;
    } else {
        const int j = idx - 65536;            // 0 .. 8*65536-1
        const int e = j >> 16, rem = j & 65535;
        const int n = rem >> 8, k = rem & 255;
        Wc1t[(e << 16) + n * 256 + k] = rtn_bf16(Wc1[(e << 16) + k * 256 + n]);
    }
}

// ---------------------------------------------------------------------------
// Phase A: h = relu(x@W1+b1) via f16 2-split / 3-product MFMA (fp32-class,
// needed for tau-threshold routing); logits = h@W2+b2 fp32; routing.
// HB=1: h -> hbuf as bf16 (expert input); f32 h -> out_h only for non-routed
// rows (after routing, from live acc). HB=0: legacy f32 out_h for all rows.
// ---------------------------------------------------------------------------
template <int HB>
__global__ __launch_bounds__(512, 4)
void root_kernel(const float* __restrict__ x,
                 const unsigned short* __restrict__ Wt0,
                 const unsigned short* __restrict__ Wt1,
                 const float* __restrict__ b1, const float* __restrict__ W2,
                 const float* __restrict__ b2, const float* __restrict__ tau,
                 float* __restrict__ out_logits, float* __restrict__ out_h,
                 float* __restrict__ out_depth, int* __restrict__ cnt,
                 int* __restrict__ lists, unsigned short* __restrict__ hbuf)
{
    __shared__ unsigned short sA0[128 * LDA], sA1[128 * LDA];   // 20.5 KB
    __shared__ float sP[128][8];                                // 4 KB
    __shared__ int   sCnt[8], sBase[8], sBest[128], sSlot[128];

    const int t    = threadIdx.x;
    const int lane = t & 63;
    const int w    = t >> 6;
    const int tx   = lane & 15;
    const int q    = lane >> 4;
    const long r0  = (long)blockIdx.x * 128;

    if (t < 8) sCnt[t] = 0;
    ((float*)sP)[t] = 0.0f;
    ((float*)sP)[t + 512] = 0.0f;

    const int colA = w * 32 + tx;
    const int colB = colA + 16;
    const unsigned short* bp0 = Wt0 + colA * 256 + q * 8;  // G0 colA
    const unsigned short* bp1 = Wt1 + colA * 256 + q * 8;  // G1 colA
    const unsigned short* bp2 = Wt0 + colB * 256 + q * 8;  // G0 colB
    const unsigned short* bp3 = Wt1 + colB * 256 + q * 8;  // G1 colB

    f32x4 acc[8][2];
#pragma unroll
    for (int mt = 0; mt < 8; mt++)
#pragma unroll
        for (int nt = 0; nt < 2; nt++) acc[mt][nt] = (f32x4)0.0f;

    // staging map: thread t covers rows ar and ar+64 at float4-slot ak
    const int ar = t >> 3, ak = t & 7;
    const float4* xr0 = (const float4*)x + (r0 + ar) * 64 + ak;
    const float4* xr1 = (const float4*)x + (r0 + 64 + ar) * 64 + ak;
    float4 xv0 = xr0[0];
    float4 xv1 = xr1[0];

    for (int i = 0; i < 8; i++) {
        if (i) __syncthreads();             // previous iter's reads complete
        {
            unsigned short h0[4], h1[4];
            split2h(xv0.x, h0[0], h1[0]);
            split2h(xv0.y, h0[1], h1[1]);
            split2h(xv0.z, h0[2], h1[2]);
            split2h(xv0.w, h0[3], h1[3]);
            *(ushort4*)&sA0[ar * LDA + ak * 4] = make_ushort4(h0[0], h0[1], h0[2], h0[3]);
            *(ushort4*)&sA1[ar * LDA + ak * 4] = make_ushort4(h1[0], h1[1], h1[2], h1[3]);
            split2h(xv1.x, h0[0], h1[0]);
            split2h(xv1.y, h0[1], h1[1]);
            split2h(xv1.z, h0[2], h1[2]);
            split2h(xv1.w, h0[3], h1[3]);
            *(ushort4*)&sA0[(64 + ar) * LDA + ak * 4] = make_ushort4(h0[0], h0[1], h0[2], h0[3]);
            *(ushort4*)&sA1[(64 + ar) * LDA + ak * 4] = make_ushort4(h1[0], h1[1], h1[2], h1[3]);
        }
        if (i < 7) { xv0 = xr0[(i + 1) * 8]; xv1 = xr1[(i + 1) * 8]; }
        __syncthreads();

        const int ko = i * 32;
        const f16x8 B0 = *(const f16x8*)(bp0 + ko);
        const f16x8 B1 = *(const f16x8*)(bp1 + ko);
        const f16x8 B2 = *(const f16x8*)(bp2 + ko);
        const f16x8 B3 = *(const f16x8*)(bp3 + ko);

#pragma unroll
        for (int mt = 0; mt < 8; mt++) {
            const f16x8 A0 = *(const f16x8*)&sA0[(mt * 16 + tx) * LDA + q * 8];
            const f16x8 A1 = *(const f16x8*)&sA1[(mt * 16 + tx) * LDA + q * 8];
            // (A0+A1)(G0+G1) ~= A0G0 + A0G1 + A1G0   (drop A1G1 ~ 2^-22)
            acc[mt][0] = __builtin_amdgcn_mfma_f32_16x16x32_f16(A0, B0, acc[mt][0], 0, 0, 0);
            acc[mt][0] = __builtin_amdgcn_mfma_f32_16x16x32_f16(A0, B1, acc[mt][0], 0, 0, 0);
            acc[mt][0] = __builtin_amdgcn_mfma_f32_16x16x32_f16(A1, B0, acc[mt][0], 0, 0, 0);
            acc[mt][1] = __builtin_amdgcn_mfma_f32_16x16x32_f16(A0, B2, acc[mt][1], 0, 0, 0);
            acc[mt][1] = __builtin_amdgcn_mfma_f32_16x16x32_f16(A0, B3, acc[mt][1], 0, 0, 0);
            acc[mt][1] = __builtin_amdgcn_mfma_f32_16x16x32_f16(A1, B2, acc[mt][1], 0, 0, 0);
        }
    }

    // ---- epilogue: bias+relu, store h (bf16 hbuf or f32), head partials ----
    const float b1c0 = b1[colA], b1c1 = b1[colB];
    float w20[8], w21[8];
    {
        const float4 a0 = ((const float4*)W2)[colA * 2];
        const float4 a1 = ((const float4*)W2)[colA * 2 + 1];
        const float4 c0 = ((const float4*)W2)[colB * 2];
        const float4 c1 = ((const float4*)W2)[colB * 2 + 1];
        w20[0]=a0.x; w20[1]=a0.y; w20[2]=a0.z; w20[3]=a0.w;
        w20[4]=a1.x; w20[5]=a1.y; w20[6]=a1.z; w20[7]=a1.w;
        w21[0]=c0.x; w21[1]=c0.y; w21[2]=c0.z; w21[3]=c0.w;
        w21[4]=c1.x; w21[5]=c1.y; w21[6]=c1.z; w21[7]=c1.w;
    }

#pragma unroll
    for (int mt = 0; mt < 8; mt++) {
        float pm[4][8];
#pragma unroll
        for (int reg = 0; reg < 4; reg++) {
            const float h0 = fmaxf(acc[mt][0][reg] + b1c0, 0.0f);
            const float h1 = fmaxf(acc[mt][1][reg] + b1c1, 0.0f);
            const int row = mt * 16 + q * 4 + reg;
            if (HB) {
                hbuf[(r0 + row) * 256 + colA] = rtn_bf16(h0);
                hbuf[(r0 + row) * 256 + colB] = rtn_bf16(h1);
            } else {
                out_h[(r0 + row) * 256 + colA] = h0;
                out_h[(r0 + row) * 256 + colB] = h1;
            }
#pragma unroll
            for (int c = 0; c < 8; c++)
                pm[reg][c] = h0 * w20[c] + h1 * w21[c];
        }
#pragma unroll
        for (int reg = 0; reg < 4; reg++)
#pragma unroll
            for (int c = 0; c < 8; c++) {
                float v = pm[reg][c];
                v += __shfl_xor(v, 1, 16);
                v += __shfl_xor(v, 2, 16);
                v += __shfl_xor(v, 4, 16);
                v += __shfl_xor(v, 8, 16);
                if (tx == 0) atomicAdd(&sP[mt * 16 + q * 4 + reg][c], v);
            }
    }
    __syncthreads();

    // ---- routing: one thread per row ----
    if (t < 128) {
        const long row = r0 + t;
        float l[8];
        float mx = -1e30f;
#pragma unroll
        for (int c = 0; c < 8; c++) {
            l[c] = sP[t][c] + b2[c];
            mx = fmaxf(mx, l[c]);
        }
        float e[8], s = 0.0f;
#pragma unroll
        for (int c = 0; c < 8; c++) { e[c] = expf(l[c] - mx); s += e[c]; }
        const float inv = 1.0f / s;
        int best = 0; float bp = -1.0f;
#pragma unroll
        for (int c = 0; c < 8; c++) {
            const float pr = e[c] * inv;
            const float m  = (pr >= tau[c]) ? pr : -1.0f;
            if (m > bp) { bp = m; best = c; }   // strict > == first max (jnp.argmax)
        }
        const bool routed = (bp >= 0.0f);
        float4* lo4 = (float4*)&out_logits[row * 8];
        lo4[0] = make_float4(l[0], l[1], l[2], l[3]);
        lo4[1] = make_float4(l[4], l[5], l[6], l[7]);
        out_depth[row] = routed ? 1.0f : 0.0f;
        if (routed) {
            sSlot[t] = atomicAdd(&sCnt[best], 1);
            sBest[t] = best;
        } else {
            sBest[t] = -1;
        }
    }
    __syncthreads();
    if (t < 8) sBase[t] = sCnt[t] ? atomicAdd(&cnt[t], sCnt[t]) : 0;
    if (HB) {
        // non-routed rows keep root h in fp32 (expert never touches them)
#pragma unroll
        for (int mt = 0; mt < 8; mt++)
#pragma unroll
            for (int reg = 0; reg < 4; reg++) {
                const int row = mt * 16 + q * 4 + reg;
                if (sBest[row] < 0) {
                    out_h[(r0 + row) * 256 + colA] = fmaxf(acc[mt][0][reg] + b1c0, 0.0f);
                    out_h[(r0 + row) * 256 + colB] = fmaxf(acc[mt][1][reg] + b1c1, 0.0f);
                }
            }
    }
    __syncthreads();
    if (t < 128 && sBest[t] >= 0) {
        const int e = sBest[t];
        lists[(long)e * Bn + sBase[e] + sSlot[t]] = (int)(r0 + t);
    }
}

// ---------------------------------------------------------------------------
// Phase B: routed rows of expert e: h_c = relu(h@Wc1[e]+bc1[e]) in PLAIN bf16
// (error ~4e-3 << 8.4e-2 threshold); l_c = h_c@Wc2[e]+bc2[e] fp32.
// Tile = 64 rows (2x block parallelism), double-buffered LDS A.
// HB=1: gather pre-rounded bf16 rows from hbuf (half the fetch, no cvt VALU).
// ---------------------------------------------------------------------------
template <int HB>
__global__ __launch_bounds__(512, 4)
void expert_kernel(const unsigned short* __restrict__ Wc1t,
                   const float* __restrict__ bc1,
                   const float* __restrict__ Wc2, const float* __restrict__ bc2,
                   float* __restrict__ out_logits, float* __restrict__ out_h,
                   const int* __restrict__ cnt, const int* __restrict__ lists,
                   const unsigned short* __restrict__ hbuf)
{
    const int e = blockIdx.y;
    const int n = cnt[e];
    const int tile0 = blockIdx.x * 64;
    if (tile0 >= n) return;
    const int nrows = min(64, n - tile0);

    __shared__ unsigned short sA[2][64 * LDA];    // 10.25 KB
    __shared__ float sP[64][8];                   // 2 KB
    __shared__ int   sRidx[64];

    const int t    = threadIdx.x;
    const int lane = t & 63;
    const int w    = t >> 6;
    const int tx   = lane & 15;
    const int q    = lane >> 4;

    if (t < 64) sRidx[t] = lists[(long)e * Bn + tile0 + min(t, nrows - 1)];
    ((float*)sP)[t] = 0.0f;

    const unsigned short* W = Wc1t + (long)e * 65536;
    const int colA = w * 32 + tx;
    const int colB = colA + 16;
    const unsigned short* bpA = W + colA * 256 + q * 8;
    const unsigned short* bpB = W + colB * 256 + q * 8;

    f32x4 acc[4][2];
#pragma unroll
    for (int mt = 0; mt < 4; mt++)
#pragma unroll
        for (int nt = 0; nt < 2; nt++) acc[mt][nt] = (f32x4)0.0f;

    // staging map: thread t covers row ar at ushort4-slot ak (32 k per iter)
    const int ar = t >> 3, ak = t & 7;
    __syncthreads();   // sRidx visible

    const unsigned short* hrB = hbuf + (long)sRidx[ar] * 256 + ak * 4;  // HB=1
    const float4*         hrF = (const float4*)out_h + (long)sRidx[ar] * 64 + ak; // HB=0

    ushort4 xv;
    if (HB) xv = *(const ushort4*)(hrB);
    else    xv = cvt4(hrF[0]);
    *(ushort4*)&sA[0][ar * LDA + ak * 4] = xv;
    if (HB) xv = *(const ushort4*)(hrB + 32);
    else    xv = cvt4(hrF[8]);
    bf16x8 BcA = *(const bf16x8*)(bpA);
    bf16x8 BcB = *(const bf16x8*)(bpB);
    __syncthreads();

#pragma unroll 2
    for (int i = 0; i < 8; i++) {
        const int cur = i & 1;
        if (i < 7) {
            *(ushort4*)&sA[cur ^ 1][ar * LDA + ak * 4] = xv;
            if (i < 6) {
                if (HB) xv = *(const ushort4*)(hrB + (i + 2) * 32);
                else    xv = cvt4(hrF[(i + 2) * 8]);
            }
        }
        bf16x8 BnA, BnB;
        if (i < 7) {
            BnA = *(const bf16x8*)(bpA + (i + 1) * 32);
            BnB = *(const bf16x8*)(bpB + (i + 1) * 32);
        }
#pragma unroll
        for (int mt = 0; mt < 4; mt++) {
            const bf16x8 A = *(const bf16x8*)&sA[cur][(mt * 16 + tx) * LDA + q * 8];
            acc[mt][0] = __builtin_amdgcn_mfma_f32_16x16x32_bf16(A, BcA, acc[mt][0], 0, 0, 0);
            acc[mt][1] = __builtin_amdgcn_mfma_f32_16x16x32_bf16(A, BcB, acc[mt][1], 0, 0, 0);
        }
        if (i < 7) { BcA = BnA; BcB = BnB; }
        __syncthreads();
    }

    // ---- epilogue ----
    const float* bc1e = bc1 + (long)e * Hn;
    const float b1c0 = bc1e[colA], b1c1 = bc1e[colB];
    const float* W2c = Wc2 + (long)e * Hn * Cn;
    float w20[8], w21[8];
    {
        const float4 a0 = ((const float4*)W2c)[colA * 2];
        const float4 a1 = ((const float4*)W2c)[colA * 2 + 1];
        const float4 c0 = ((const float4*)W2c)[colB * 2];
        const float4 c1 = ((const float4*)W2c)[colB * 2 + 1];
        w20[0]=a0.x; w20[1]=a0.y; w20[2]=a0.z; w20[3]=a0.w;
        w20[4]=a1.x; w20[5]=a1.y; w20[6]=a1.z; w20[7]=a1.w;
        w21[0]=c0.x; w21[1]=c0.y; w21[2]=c0.z; w21[3]=c0.w;
        w21[4]=c1.x; w21[5]=c1.y; w21[6]=c1.z; w21[7]=c1.w;
    }

#pragma unroll
    for (int mt = 0; mt < 4; mt++) {
        float pm[4][8];
#pragma unroll
        for (int reg = 0; reg < 4; reg++) {
            const float h0 = fmaxf(acc[mt][0][reg] + b1c0, 0.0f);
            const float h1 = fmaxf(acc[mt][1][reg] + b1c1, 0.0f);
            const int row = mt * 16 + q * 4 + reg;
            if (row < nrows) {
                out_h[(long)sRidx[row] * 256 + colA] = h0;
                out_h[(long)sRidx[row] * 256 + colB] = h1;
            }
#pragma unroll
            for (int c = 0; c < 8; c++)
                pm[reg][c] = h0 * w20[c] + h1 * w21[c];
        }
#pragma unroll
        for (int reg = 0; reg < 4; reg++)
#pragma unroll
            for (int c = 0; c < 8; c++) {
                float v = pm[reg][c];
                v += __shfl_xor(v, 1, 16);
                v += __shfl_xor(v, 2, 16);
                v += __shfl_xor(v, 4, 16);
                v += __shfl_xor(v, 8, 16);
                if (tx == 0) atomicAdd(&sP[mt * 16 + q * 4 + reg][c], v);
            }
    }
    __syncthreads();

    if (t < nrows) {
        const long row = sRidx[t];
        const float* bc2e = bc2 + (long)e * Cn;
        float4* lo4 = (float4*)&out_logits[row * 8];
        lo4[0] = make_float4(sP[t][0] + bc2e[0], sP[t][1] + bc2e[1],
                             sP[t][2] + bc2e[2], sP[t][3] + bc2e[3]);
        lo4[1] = make_float4(sP[t][4] + bc2e[4], sP[t][5] + bc2e[5],
                             sP[t][6] + bc2e[6], sP[t][7] + bc2e[7]);
    }
}

extern "C" void kernel_launch(void* const* d_in, const int* in_sizes, int n_in,
                              void* d_out, int out_size, void* d_ws, size_t ws_size,
                              hipStream_t stream)
{
    const float* x   = (const float*)d_in[0];
    const float* W1  = (const float*)d_in[1];
    const float* b1  = (const float*)d_in[2];
    const float* W2  = (const float*)d_in[3];
    const float* b2  = (const float*)d_in[4];
    const float* Wc1 = (const float*)d_in[5];
    const float* bc1 = (const float*)d_in[6];
    const float* Wc2 = (const float*)d_in[7];
    const float* bc2 = (const float*)d_in[8];
    const float* tau = (const float*)d_in[9];

    float* out_logits = (float*)d_out;                       // [B, 8]
    float* out_h      = out_logits + (long)Bn * Cn;          // [B, 256]
    float* out_depth  = out_h + (long)Bn * Hn;               // [B]

    char* wsb = (char*)d_ws;
    int* cnt   = (int*)wsb;                                  // 8 counters
    int* lists = (int*)(wsb + 128);                          // 8 x B ints (4MB)
    unsigned short* W1t0 = (unsigned short*)(wsb + 128 + (size_t)8 * Bn * 4);
    unsigned short* W1t1 = W1t0 + 65536;
    unsigned short* Wc1t = W1t1 + 65536;                     // 8 x 65536 bf16
    unsigned short* hbuf = Wc1t + 8 * 65536;                 // [B,256] bf16 (67MB)

    const size_t need_hbuf = (size_t)((char*)(hbuf + (size_t)Bn * 256) - wsb);
    const bool   use_hbuf  = ws_size >= need_hbuf;

    hipMemsetAsync(d_ws, 0, 128, stream);

    prep_kernel<<<dim3((65536 + 8 * 65536) / 256), 256, 0, stream>>>(
        W1, Wc1, W1t0, W1t1, Wc1t);

    if (use_hbuf) {
        root_kernel<1><<<dim3(Bn / 128), 512, 0, stream>>>(
            x, W1t0, W1t1, b1, W2, b2, tau, out_logits, out_h, out_depth,
            cnt, lists, hbuf);
        expert_kernel<1><<<dim3(Bn / 64, 8), 512, 0, stream>>>(
            Wc1t, bc1, Wc2, bc2, out_logits, out_h, cnt, lists, hbuf);
    } else {
        root_kernel<0><<<dim3(Bn / 128), 512, 0, stream>>>(
            x, W1t0, W1t1, b1, W2, b2, tau, out_logits, out_h, out_depth,
            cnt, lists, hbuf);
        expert_kernel<0><<<dim3(Bn / 64, 8), 512, 0, stream>>>(
            Wc1t, bc1, Wc2, bc2, out_logits, out_h, cnt, lists, hbuf);
    }
}

// Round 7
// 558.550 us; speedup vs baseline: 1.4802x; 1.0100x over previous
//
#include <hip/hip_runtime.h>

// Problem constants
#define Bn 131072
#define Dn 256
#define Hn 256
#define Cn 8

typedef __attribute__((ext_vector_type(4))) float f32x4;
typedef __attribute__((ext_vector_type(8))) __bf16 bf16x8;
typedef _Float16 f16;
typedef __attribute__((ext_vector_type(8))) _Float16 f16x8;

#define LDA 40   // LDS row stride in bf16/f16 units (80B): <=2-way bank aliasing = free
#define LDH 264  // epilogue sH stride in shorts: 132 dwords == 4 mod 32 -> rows shift banks

// ---- bf16 helpers (round-to-nearest-even) ----
__device__ inline unsigned short rtn_bf16(float v) {
    unsigned int u = __float_as_uint(v);
    unsigned int r = u + 0x7fffu + ((u >> 16) & 1u);
    return (unsigned short)(r >> 16);
}
__device__ inline float bf16_to_f(unsigned short h) {
    return __uint_as_float((unsigned int)h << 16);
}
__device__ inline ushort4 cvt4(float4 v) {
    return make_ushort4(rtn_bf16(v.x), rtn_bf16(v.y), rtn_bf16(v.z), rtn_bf16(v.w));
}
// ---- f16 2-split: v = h0 + h1 + O(2^-24 v).  (f32->f16 cast is RTN.) ----
__device__ inline void split2h(float v, unsigned short& a0, unsigned short& a1) {
    const f16 h0 = (f16)v;
    const f16 h1 = (f16)(v - (float)h0);
    a0 = __builtin_bit_cast(unsigned short, h0);
    a1 = __builtin_bit_cast(unsigned short, h1);
}

// ---------------------------------------------------------------------------
// Prep: W1[k][n] -> 2 f16 splits transposed [n][k] (routing-accurate path);
//       Wc1[e][k][n] -> single bf16 transposed [e][n][k] (value-accurate path).
// ---------------------------------------------------------------------------
__global__ __launch_bounds__(256)
void prep_kernel(const float* __restrict__ W1, const float* __restrict__ Wc1,
                 unsigned short* __restrict__ W1t0, unsigned short* __restrict__ W1t1,
                 unsigned short* __restrict__ Wc1t)
{
    const int idx = blockIdx.x * 256 + threadIdx.x;
    if (idx < 65536) {
        const int n = idx >> 8, k = idx & 255;
        unsigned short a0, a1;
        split2h(W1[k * 256 + n], a0, a1);
        W1t0[idx] = a0; W1t1[idx] = a1;
    } else {
        const int j = idx - 65536;            // 0 .. 8*65536-1
        const int e = j >> 16, rem = j & 65535;
        const int n = rem >> 8, k = rem & 255;
        Wc1t[(e << 16) + n * 256 + k] = rtn_bf16(Wc1[(e << 16) + k * 256 + n]);
    }
}

// ---------------------------------------------------------------------------
// Phase A: h = relu(x@W1+b1) via f16 2-split / 3-product MFMA (fp32-class,
// needed for tau-threshold routing); logits = h@W2+b2 fp32; routing.
// HB=1: h -> hbuf as bf16, staged through LDS (union over the dead k-loop
// A-buffers) and written out fully coalesced (16B/lane, full 128B lines);
// f32 h -> out_h only for non-routed rows. HB=0: legacy f32 out_h for all.
// ---------------------------------------------------------------------------
template <int HB>
__global__ __launch_bounds__(512, 4)
void root_kernel(const float* __restrict__ x,
                 const unsigned short* __restrict__ Wt0,
                 const unsigned short* __restrict__ Wt1,
                 const float* __restrict__ b1, const float* __restrict__ W2,
                 const float* __restrict__ b2, const float* __restrict__ tau,
                 float* __restrict__ out_logits, float* __restrict__ out_h,
                 float* __restrict__ out_depth, int* __restrict__ cnt,
                 int* __restrict__ lists, unsigned short* __restrict__ hbuf)
{
    __shared__ union {
        unsigned short A[2][128 * LDA];   // 20.5 KB k-loop staging
        unsigned short H[64 * LDH];       // 33 KB epilogue bf16 h chunk
    } sU;
    __shared__ float sP[128][8];                                // 4 KB
    __shared__ int   sCnt[8], sBase[8], sBest[128], sSlot[128];

    const int t    = threadIdx.x;
    const int lane = t & 63;
    const int w    = t >> 6;
    const int tx   = lane & 15;
    const int q    = lane >> 4;
    const long r0  = (long)blockIdx.x * 128;

    if (t < 8) sCnt[t] = 0;
    ((float*)sP)[t] = 0.0f;
    ((float*)sP)[t + 512] = 0.0f;

    const int colA = w * 32 + tx;
    const int colB = colA + 16;
    const unsigned short* bp0 = Wt0 + colA * 256 + q * 8;  // G0 colA
    const unsigned short* bp1 = Wt1 + colA * 256 + q * 8;  // G1 colA
    const unsigned short* bp2 = Wt0 + colB * 256 + q * 8;  // G0 colB
    const unsigned short* bp3 = Wt1 + colB * 256 + q * 8;  // G1 colB

    f32x4 acc[8][2];
#pragma unroll
    for (int mt = 0; mt < 8; mt++)
#pragma unroll
        for (int nt = 0; nt < 2; nt++) acc[mt][nt] = (f32x4)0.0f;

    // staging map: thread t covers rows ar and ar+64 at float4-slot ak
    const int ar = t >> 3, ak = t & 7;
    const float4* xr0 = (const float4*)x + (r0 + ar) * 64 + ak;
    const float4* xr1 = (const float4*)x + (r0 + 64 + ar) * 64 + ak;
    float4 xv0 = xr0[0];
    float4 xv1 = xr1[0];

    for (int i = 0; i < 8; i++) {
        if (i) __syncthreads();             // previous iter's reads complete
        {
            unsigned short h0[4], h1[4];
            split2h(xv0.x, h0[0], h1[0]);
            split2h(xv0.y, h0[1], h1[1]);
            split2h(xv0.z, h0[2], h1[2]);
            split2h(xv0.w, h0[3], h1[3]);
            *(ushort4*)&sU.A[0][ar * LDA + ak * 4] = make_ushort4(h0[0], h0[1], h0[2], h0[3]);
            *(ushort4*)&sU.A[1][ar * LDA + ak * 4] = make_ushort4(h1[0], h1[1], h1[2], h1[3]);
            split2h(xv1.x, h0[0], h1[0]);
            split2h(xv1.y, h0[1], h1[1]);
            split2h(xv1.z, h0[2], h1[2]);
            split2h(xv1.w, h0[3], h1[3]);
            *(ushort4*)&sU.A[0][(64 + ar) * LDA + ak * 4] = make_ushort4(h0[0], h0[1], h0[2], h0[3]);
            *(ushort4*)&sU.A[1][(64 + ar) * LDA + ak * 4] = make_ushort4(h1[0], h1[1], h1[2], h1[3]);
        }
        if (i < 7) { xv0 = xr0[(i + 1) * 8]; xv1 = xr1[(i + 1) * 8]; }
        __syncthreads();

        const int ko = i * 32;
        const f16x8 B0 = *(const f16x8*)(bp0 + ko);
        const f16x8 B1 = *(const f16x8*)(bp1 + ko);
        const f16x8 B2 = *(const f16x8*)(bp2 + ko);
        const f16x8 B3 = *(const f16x8*)(bp3 + ko);

#pragma unroll
        for (int mt = 0; mt < 8; mt++) {
            const f16x8 A0 = *(const f16x8*)&sU.A[0][(mt * 16 + tx) * LDA + q * 8];
            const f16x8 A1 = *(const f16x8*)&sU.A[1][(mt * 16 + tx) * LDA + q * 8];
            // (A0+A1)(G0+G1) ~= A0G0 + A0G1 + A1G0   (drop A1G1 ~ 2^-22)
            acc[mt][0] = __builtin_amdgcn_mfma_f32_16x16x32_f16(A0, B0, acc[mt][0], 0, 0, 0);
            acc[mt][0] = __builtin_amdgcn_mfma_f32_16x16x32_f16(A0, B1, acc[mt][0], 0, 0, 0);
            acc[mt][0] = __builtin_amdgcn_mfma_f32_16x16x32_f16(A1, B0, acc[mt][0], 0, 0, 0);
            acc[mt][1] = __builtin_amdgcn_mfma_f32_16x16x32_f16(A0, B2, acc[mt][1], 0, 0, 0);
            acc[mt][1] = __builtin_amdgcn_mfma_f32_16x16x32_f16(A0, B3, acc[mt][1], 0, 0, 0);
            acc[mt][1] = __builtin_amdgcn_mfma_f32_16x16x32_f16(A1, B2, acc[mt][1], 0, 0, 0);
        }
    }
    __syncthreads();   // all waves done with sU.A (safe to reuse as sU.H)

    // ---- epilogue: bias+relu, store h (bf16 hbuf via LDS, or f32), partials ----
    const float b1c0 = b1[colA], b1c1 = b1[colB];
    float w20[8], w21[8];
    {
        const float4 a0 = ((const float4*)W2)[colA * 2];
        const float4 a1 = ((const float4*)W2)[colA * 2 + 1];
        const float4 c0 = ((const float4*)W2)[colB * 2];
        const float4 c1 = ((const float4*)W2)[colB * 2 + 1];
        w20[0]=a0.x; w20[1]=a0.y; w20[2]=a0.z; w20[3]=a0.w;
        w20[4]=a1.x; w20[5]=a1.y; w20[6]=a1.z; w20[7]=a1.w;
        w21[0]=c0.x; w21[1]=c0.y; w21[2]=c0.z; w21[3]=c0.w;
        w21[4]=c1.x; w21[5]=c1.y; w21[6]=c1.z; w21[7]=c1.w;
    }

    if (HB) {
        // two 64-row chunks: bf16 h -> LDS -> coalesced 16B global stores
#pragma unroll
        for (int chunk = 0; chunk < 2; chunk++) {
            if (chunk) __syncthreads();        // prev chunk copy-out done
#pragma unroll
            for (int m4 = 0; m4 < 4; m4++) {
                const int mt = chunk * 4 + m4;
                float pm[4][8];
#pragma unroll
                for (int reg = 0; reg < 4; reg++) {
                    const float h0 = fmaxf(acc[mt][0][reg] + b1c0, 0.0f);
                    const float h1 = fmaxf(acc[mt][1][reg] + b1c1, 0.0f);
                    const int lrow = m4 * 16 + q * 4 + reg;   // row within chunk
                    sU.H[lrow * LDH + colA] = rtn_bf16(h0);
                    sU.H[lrow * LDH + colB] = rtn_bf16(h1);
#pragma unroll
                    for (int c = 0; c < 8; c++)
                        pm[reg][c] = h0 * w20[c] + h1 * w21[c];
                }
#pragma unroll
                for (int reg = 0; reg < 4; reg++)
#pragma unroll
                    for (int c = 0; c < 8; c++) {
                        float v = pm[reg][c];
                        v += __shfl_xor(v, 1, 16);
                        v += __shfl_xor(v, 2, 16);
                        v += __shfl_xor(v, 4, 16);
                        v += __shfl_xor(v, 8, 16);
                        if (tx == 0) atomicAdd(&sP[mt * 16 + q * 4 + reg][c], v);
                    }
            }
            __syncthreads();                   // chunk's H tile complete
            unsigned short* dst = hbuf + (r0 + chunk * 64) * 256;
#pragma unroll
            for (int k = 0; k < 4; k++) {
                const int row = k * 16 + (t >> 5);
                const int col = (t & 31) * 8;
                *(uint4*)(dst + row * 256 + col) = *(const uint4*)&sU.H[row * LDH + col];
            }
        }
    } else {
#pragma unroll
        for (int mt = 0; mt < 8; mt++) {
            float pm[4][8];
#pragma unroll
            for (int reg = 0; reg < 4; reg++) {
                const float h0 = fmaxf(acc[mt][0][reg] + b1c0, 0.0f);
                const float h1 = fmaxf(acc[mt][1][reg] + b1c1, 0.0f);
                const int row = mt * 16 + q * 4 + reg;
                out_h[(r0 + row) * 256 + colA] = h0;
                out_h[(r0 + row) * 256 + colB] = h1;
#pragma unroll
                for (int c = 0; c < 8; c++)
                    pm[reg][c] = h0 * w20[c] + h1 * w21[c];
            }
#pragma unroll
            for (int reg = 0; reg < 4; reg++)
#pragma unroll
                for (int c = 0; c < 8; c++) {
                    float v = pm[reg][c];
                    v += __shfl_xor(v, 1, 16);
                    v += __shfl_xor(v, 2, 16);
                    v += __shfl_xor(v, 4, 16);
                    v += __shfl_xor(v, 8, 16);
                    if (tx == 0) atomicAdd(&sP[mt * 16 + q * 4 + reg][c], v);
                }
        }
    }
    __syncthreads();

    // ---- routing: one thread per row ----
    if (t < 128) {
        const long row = r0 + t;
        float l[8];
        float mx = -1e30f;
#pragma unroll
        for (int c = 0; c < 8; c++) {
            l[c] = sP[t][c] + b2[c];
            mx = fmaxf(mx, l[c]);
        }
        float e[8], s = 0.0f;
#pragma unroll
        for (int c = 0; c < 8; c++) { e[c] = expf(l[c] - mx); s += e[c]; }
        const float inv = 1.0f / s;
        int best = 0; float bp = -1.0f;
#pragma unroll
        for (int c = 0; c < 8; c++) {
            const float pr = e[c] * inv;
            const float m  = (pr >= tau[c]) ? pr : -1.0f;
            if (m > bp) { bp = m; best = c; }   // strict > == first max (jnp.argmax)
        }
        const bool routed = (bp >= 0.0f);
        float4* lo4 = (float4*)&out_logits[row * 8];
        lo4[0] = make_float4(l[0], l[1], l[2], l[3]);
        lo4[1] = make_float4(l[4], l[5], l[6], l[7]);
        out_depth[row] = routed ? 1.0f : 0.0f;
        if (routed) {
            sSlot[t] = atomicAdd(&sCnt[best], 1);
            sBest[t] = best;
        } else {
            sBest[t] = -1;
        }
    }
    __syncthreads();
    if (t < 8) sBase[t] = sCnt[t] ? atomicAdd(&cnt[t], sCnt[t]) : 0;
    if (HB) {
        // non-routed rows keep root h in fp32 (expert never touches them)
#pragma unroll
        for (int mt = 0; mt < 8; mt++)
#pragma unroll
            for (int reg = 0; reg < 4; reg++) {
                const int row = mt * 16 + q * 4 + reg;
                if (sBest[row] < 0) {
                    out_h[(r0 + row) * 256 + colA] = fmaxf(acc[mt][0][reg] + b1c0, 0.0f);
                    out_h[(r0 + row) * 256 + colB] = fmaxf(acc[mt][1][reg] + b1c1, 0.0f);
                }
            }
    }
    __syncthreads();
    if (t < 128 && sBest[t] >= 0) {
        const int e = sBest[t];
        lists[(long)e * Bn + sBase[e] + sSlot[t]] = (int)(r0 + t);
    }
}

// ---------------------------------------------------------------------------
// Phase B: routed rows of expert e: h_c = relu(h@Wc1[e]+bc1[e]) in PLAIN bf16
// (error ~4e-3 << 8.4e-2 threshold); l_c = h_c@Wc2[e]+bc2[e] fp32.
// Tile = 64 rows (2x block parallelism), double-buffered LDS A.
// HB=1: gather pre-rounded bf16 rows from hbuf (half the fetch, no cvt VALU).
// ---------------------------------------------------------------------------
template <int HB>
__global__ __launch_bounds__(512, 4)
void expert_kernel(const unsigned short* __restrict__ Wc1t,
                   const float* __restrict__ bc1,
                   const float* __restrict__ Wc2, const float* __restrict__ bc2,
                   float* __restrict__ out_logits, float* __restrict__ out_h,
                   const int* __restrict__ cnt, const int* __restrict__ lists,
                   const unsigned short* __restrict__ hbuf)
{
    const int e = blockIdx.y;
    const int n = cnt[e];
    const int tile0 = blockIdx.x * 64;
    if (tile0 >= n) return;
    const int nrows = min(64, n - tile0);

    __shared__ unsigned short sA[2][64 * LDA];    // 10.25 KB
    __shared__ float sP[64][8];                   // 2 KB
    __shared__ int   sRidx[64];

    const int t    = threadIdx.x;
    const int lane = t & 63;
    const int w    = t >> 6;
    const int tx   = lane & 15;
    const int q    = lane >> 4;

    if (t < 64) sRidx[t] = lists[(long)e * Bn + tile0 + min(t, nrows - 1)];
    ((float*)sP)[t] = 0.0f;

    const unsigned short* W = Wc1t + (long)e * 65536;
    const int colA = w * 32 + tx;
    const int colB = colA + 16;
    const unsigned short* bpA = W + colA * 256 + q * 8;
    const unsigned short* bpB = W + colB * 256 + q * 8;

    f32x4 acc[4][2];
#pragma unroll
    for (int mt = 0; mt < 4; mt++)
#pragma unroll
        for (int nt = 0; nt < 2; nt++) acc[mt][nt] = (f32x4)0.0f;

    // staging map: thread t covers row ar at ushort4-slot ak (32 k per iter)
    const int ar = t >> 3, ak = t & 7;
    __syncthreads();   // sRidx visible

    const unsigned short* hrB = hbuf + (long)sRidx[ar] * 256 + ak * 4;  // HB=1
    const float4*         hrF = (const float4*)out_h + (long)sRidx[ar] * 64 + ak; // HB=0

    ushort4 xv;
    if (HB) xv = *(const ushort4*)(hrB);
    else    xv = cvt4(hrF[0]);
    *(ushort4*)&sA[0][ar * LDA + ak * 4] = xv;
    if (HB) xv = *(const ushort4*)(hrB + 32);
    else    xv = cvt4(hrF[8]);
    bf16x8 BcA = *(const bf16x8*)(bpA);
    bf16x8 BcB = *(const bf16x8*)(bpB);
    __syncthreads();

#pragma unroll 2
    for (int i = 0; i < 8; i++) {
        const int cur = i & 1;
        if (i < 7) {
            *(ushort4*)&sA[cur ^ 1][ar * LDA + ak * 4] = xv;
            if (i < 6) {
                if (HB) xv = *(const ushort4*)(hrB + (i + 2) * 32);
                else    xv = cvt4(hrF[(i + 2) * 8]);
            }
        }
        bf16x8 BnA, BnB;
        if (i < 7) {
            BnA = *(const bf16x8*)(bpA + (i + 1) * 32);
            BnB = *(const bf16x8*)(bpB + (i + 1) * 32);
        }
#pragma unroll
        for (int mt = 0; mt < 4; mt++) {
            const bf16x8 A = *(const bf16x8*)&sA[cur][(mt * 16 + tx) * LDA + q * 8];
            acc[mt][0] = __builtin_amdgcn_mfma_f32_16x16x32_bf16(A, BcA, acc[mt][0], 0, 0, 0);
            acc[mt][1] = __builtin_amdgcn_mfma_f32_16x16x32_bf16(A, BcB, acc[mt][1], 0, 0, 0);
        }
        if (i < 7) { BcA = BnA; BcB = BnB; }
        __syncthreads();
    }

    // ---- epilogue ----
    const float* bc1e = bc1 + (long)e * Hn;
    const float b1c0 = bc1e[colA], b1c1 = bc1e[colB];
    const float* W2c = Wc2 + (long)e * Hn * Cn;
    float w20[8], w21[8];
    {
        const float4 a0 = ((const float4*)W2c)[colA * 2];
        const float4 a1 = ((const float4*)W2c)[colA * 2 + 1];
        const float4 c0 = ((const float4*)W2c)[colB * 2];
        const float4 c1 = ((const float4*)W2c)[colB * 2 + 1];
        w20[0]=a0.x; w20[1]=a0.y; w20[2]=a0.z; w20[3]=a0.w;
        w20[4]=a1.x; w20[5]=a1.y; w20[6]=a1.z; w20[7]=a1.w;
        w21[0]=c0.x; w21[1]=c0.y; w21[2]=c0.z; w21[3]=c0.w;
        w21[4]=c1.x; w21[5]=c1.y; w21[6]=c1.z; w21[7]=c1.w;
    }

#pragma unroll
    for (int mt = 0; mt < 4; mt++) {
        float pm[4][8];
#pragma unroll
        for (int reg = 0; reg < 4; reg++) {
            const float h0 = fmaxf(acc[mt][0][reg] + b1c0, 0.0f);
            const float h1 = fmaxf(acc[mt][1][reg] + b1c1, 0.0f);
            const int row = mt * 16 + q * 4 + reg;
            if (row < nrows) {
                out_h[(long)sRidx[row] * 256 + colA] = h0;
                out_h[(long)sRidx[row] * 256 + colB] = h1;
            }
#pragma unroll
            for (int c = 0; c < 8; c++)
                pm[reg][c] = h0 * w20[c] + h1 * w21[c];
        }
#pragma unroll
        for (int reg = 0; reg < 4; reg++)
#pragma unroll
            for (int c = 0; c < 8; c++) {
                float v = pm[reg][c];
                v += __shfl_xor(v, 1, 16);
                v += __shfl_xor(v, 2, 16);
                v += __shfl_xor(v, 4, 16);
                v += __shfl_xor(v, 8, 16);
                if (tx == 0) atomicAdd(&sP[mt * 16 + q * 4 + reg][c], v);
            }
    }
    __syncthreads();

    if (t < nrows) {
        const long row = sRidx[t];
        const float* bc2e = bc2 + (long)e * Cn;
        float4* lo4 = (float4*)&out_logits[row * 8];
        lo4[0] = make_float4(sP[t][0] + bc2e[0], sP[t][1] + bc2e[1],
                             sP[t][2] + bc2e[2], sP[t][3] + bc2e[3]);
        lo4[1] = make_float4(sP[t][4] + bc2e[4], sP[t][5] + bc2e[5],
                             sP[t][6] + bc2e[6], sP[t][7] + bc2e[7]);
    }
}

extern "C" void kernel_launch(void* const* d_in, const int* in_sizes, int n_in,
                              void* d_out, int out_size, void* d_ws, size_t ws_size,
                              hipStream_t stream)
{
    const float* x   = (const float*)d_in[0];
    const float* W1  = (const float*)d_in[1];
    const float* b1  = (const float*)d_in[2];
    const float* W2  = (const float*)d_in[3];
    const float* b2  = (const float*)d_in[4];
    const float* Wc1 = (const float*)d_in[5];
    const float* bc1 = (const float*)d_in[6];
    const float* Wc2 = (const float*)d_in[7];
    const float* bc2 = (const float*)d_in[8];
    const float* tau = (const float*)d_in[9];

    float* out_logits = (float*)d_out;                       // [B, 8]
    float* out_h      = out_logits + (long)Bn * Cn;          // [B, 256]
    float* out_depth  = out_h + (long)Bn * Hn;               // [B]

    char* wsb = (char*)d_ws;
    int* cnt   = (int*)wsb;                                  // 8 counters
    int* lists = (int*)(wsb + 128);                          // 8 x B ints (4MB)
    unsigned short* W1t0 = (unsigned short*)(wsb + 128 + (size_t)8 * Bn * 4);
    unsigned short* W1t1 = W1t0 + 65536;
    unsigned short* Wc1t = W1t1 + 65536;                     // 8 x 65536 bf16
    unsigned short* hbuf = Wc1t + 8 * 65536;                 // [B,256] bf16 (67MB)

    const size_t need_hbuf = (size_t)((char*)(hbuf + (size_t)Bn * 256) - wsb);
    const bool   use_hbuf  = ws_size >= need_hbuf;

    hipMemsetAsync(d_ws, 0, 128, stream);

    prep_kernel<<<dim3((65536 + 8 * 65536) / 256), 256, 0, stream>>>(
        W1, Wc1, W1t0, W1t1, Wc1t);

    if (use_hbuf) {
        root_kernel<1><<<dim3(Bn / 128), 512, 0, stream>>>(
            x, W1t0, W1t1, b1, W2, b2, tau, out_logits, out_h, out_depth,
            cnt, lists, hbuf);
        expert_kernel<1><<<dim3(Bn / 64, 8), 512, 0, stream>>>(
            Wc1t, bc1, Wc2, bc2, out_logits, out_h, cnt, lists, hbuf);
    } else {
        root_kernel<0><<<dim3(Bn / 128), 512, 0, stream>>>(
            x, W1t0, W1t1, b1, W2, b2, tau, out_logits, out_h, out_depth,
            cnt, lists, hbuf);
        expert_kernel<0><<<dim3(Bn / 64, 8), 512, 0, stream>>>(
            Wc1t, bc1, Wc2, bc2, out_logits, out_h, cnt, lists, hbuf);
    }
}